// Round 6
// baseline (312.423 us; speedup 1.0000x reference)
//
#include <hip/hip_runtime.h>

typedef __attribute__((ext_vector_type(8))) __bf16 bf16x8;
typedef __attribute__((ext_vector_type(4))) float f32x4;
typedef __attribute__((ext_vector_type(8))) unsigned short u16x8;
typedef __attribute__((ext_vector_type(4))) unsigned short u16x4;
typedef __attribute__((ext_vector_type(2))) unsigned int u32x2;
typedef __attribute__((ext_vector_type(4))) unsigned int u32x4;

#define MFMA16(a, b, c) __builtin_amdgcn_mfma_f32_16x16x32_bf16((a), (b), (c), 0, 0, 0)

__device__ __forceinline__ unsigned short f2bf(float f) {
    unsigned int u = __float_as_uint(f);
    unsigned int r = (u + 0x7FFFu + ((u >> 16) & 1u)) >> 16;
    return (unsigned short)r;
}

__device__ __forceinline__ float fexp2(float x) {
#if __has_builtin(__builtin_amdgcn_exp2f)
    return __builtin_amdgcn_exp2f(x);
#else
    return exp2f(x);
#endif
}

// gfx950 lane-swap primitives (quad-axis data movement without LDS).
__device__ __forceinline__ u32x2 plswap32(unsigned int x, unsigned int y) {
#if __has_builtin(__builtin_amdgcn_permlane32_swap)
    return __builtin_amdgcn_permlane32_swap(x, y, false, false);
#else
    asm volatile("s_nop 1\n\tv_permlane32_swap_b32 %0, %1" : "+v"(x), "+v"(y));
    u32x2 r = {x, y};
    return r;
#endif
}
__device__ __forceinline__ u32x2 plswap16(unsigned int x, unsigned int y) {
#if __has_builtin(__builtin_amdgcn_permlane16_swap)
    return __builtin_amdgcn_permlane16_swap(x, y, false, false);
#else
    asm volatile("s_nop 1\n\tv_permlane16_swap_b32 %0, %1" : "+v"(x), "+v"(y));
    u32x2 r = {x, y};
    return r;
#endif
}

// sum across the quad axis (lanes l16, l16+16, l16+32, l16+48) via permlane swaps.
__device__ __forceinline__ float quad_reduce(float v) {
    u32x2 a = plswap32(__float_as_uint(v), __float_as_uint(v));
    v = __uint_as_float(a.x) + __uint_as_float(a.y);
    u32x2 b = plswap16(__float_as_uint(v), __float_as_uint(v));
    return __uint_as_float(b.x) + __uint_as_float(b.y);
}

// ---------------- fused prep: x->bf16 convert + 4 weight transposes ----------------
__device__ __forceinline__ void transpose_tile(const float* __restrict__ in,
                                               unsigned short* __restrict__ out,
                                               int R, int C, int bx, int by) {
    __shared__ float tile[32][33];
    const int tx = threadIdx.x & 31, ty = threadIdx.x >> 5;
    const int c0 = bx * 32, r0 = by * 32;
#pragma unroll
    for (int i = 0; i < 4; ++i)
        tile[ty + i * 8][tx] = in[(size_t)(r0 + ty + i * 8) * C + c0 + tx];
    __syncthreads();
#pragma unroll
    for (int i = 0; i < 4; ++i)
        out[(size_t)(c0 + ty + i * 8) * R + r0 + tx] = f2bf(tile[tx][ty + i * 8]);
}

__global__ __launch_bounds__(256) void k_prep(const float* __restrict__ x,
                                              const float* __restrict__ Wq,
                                              const float* __restrict__ Wkvd,
                                              const float* __restrict__ Wkvu,
                                              const float* __restrict__ Wo,
                                              unsigned short* __restrict__ xb,
                                              unsigned short* __restrict__ Wcat_t,
                                              unsigned short* __restrict__ Wkvu_t,
                                              unsigned short* __restrict__ Wo_t) {
    const int i = blockIdx.x;
    if (i < 8192) {
        const int idx = i * 256 + threadIdx.x;
        const float4 v = ((const float4*)x)[idx];
        u16x4 o = { f2bf(v.x), f2bf(v.y), f2bf(v.z), f2bf(v.w) };
        ((u16x4*)xb)[idx] = o;
    } else if (i < 12288) {
        const int j = i - 8192;
        transpose_tile(Wq, Wcat_t, 2048, 2048, j & 63, j >> 6);
    } else if (i < 13312) {
        const int j = i - 12288;
        transpose_tile(Wkvd, Wcat_t + 2048 * 2048, 2048, 512, j & 15, j >> 4);
    } else if (i < 14336) {
        const int j = i - 13312;
        transpose_tile(Wkvu, Wkvu_t, 512, 2048, j & 63, j >> 6);
    } else {
        const int j = i - 14336;
        transpose_tile(Wo, Wo_t, 2048, 2048, j & 63, j >> 6);
    }
}

// ---------------- bf16 GEMM: C[M][N] = alpha * A[M][K] @ Bt[N][K]^T ----------------
// Double-buffered LDS + single barrier per BK=32 (loads in flight across compute).
// OUT_MODE: 0 = fp32 C, 1 = bf16 C, 2 = bf16 C + transposed copy Ct (per-head d-major),
// 3 = fused q/kv_down split (col<2048 -> Cv *alpha; col>=2048 -> Ct stride 512).
template <int OUT_MODE>
__global__ __launch_bounds__(256) void k_gemm_bt(const unsigned short* __restrict__ A,
                                                 const unsigned short* __restrict__ B,
                                                 void* __restrict__ Cv,
                                                 unsigned short* __restrict__ Ct,
                                                 int M, int N, int K, float alpha) {
    __shared__ alignas(16) unsigned short As[2 * 128 * 32];
    __shared__ alignas(16) unsigned short Bs[2 * 128 * 32];
    const int tid = threadIdx.x;
    const int wave = tid >> 6;
    const int lane = tid & 63;
    const int l16 = lane & 15;
    const int quad = lane >> 4;
    const int bm = blockIdx.x * 128;  // M on x: same-XCD blocks share A-panels
    const int bn = blockIdx.y * 128;
    const int wm = (wave >> 1) * 64;
    const int wn = (wave & 1) * 64;

    const f32x4 fzero = {0.f, 0.f, 0.f, 0.f};
    f32x4 acc[4][4];
#pragma unroll
    for (int i = 0; i < 4; ++i)
#pragma unroll
        for (int j = 0; j < 4; ++j) acc[i][j] = fzero;

    auto AsL = (__attribute__((address_space(3))) unsigned short*)As;
    auto BsL = (__attribute__((address_space(3))) unsigned short*)Bs;

    const int c0 = wave * 128 + lane;

    auto stage = [&](int kt32) {
        const int boff = (kt32 & 1) * (128 * 32);
        const int kt = kt32 * 32;
#pragma unroll
        for (int j = 0; j < 2; ++j) {
            const int c = c0 + j * 64;
            __builtin_amdgcn_global_load_lds(
                (const __attribute__((address_space(1))) void*)(A + (size_t)(bm + (c >> 2)) * K + kt + (c & 3) * 8),
                (__attribute__((address_space(3))) void*)(AsL + boff + c * 8), 16, 0, 0);
            __builtin_amdgcn_global_load_lds(
                (const __attribute__((address_space(1))) void*)(B + (size_t)(bn + (c >> 2)) * K + kt + (c & 3) * 8),
                (__attribute__((address_space(3))) void*)(BsL + boff + c * 8), 16, 0, 0);
        }
    };

    const int nk = K >> 5;
    stage(0);
    for (int kt32 = 0; kt32 < nk; ++kt32) {
        __syncthreads();
        if (kt32 + 1 < nk) stage(kt32 + 1);
        const unsigned short* Ab = As + (kt32 & 1) * (128 * 32);
        const unsigned short* Bb = Bs + (kt32 & 1) * (128 * 32);

        bf16x8 af[4], bfr[4];
#pragma unroll
        for (int mt = 0; mt < 4; ++mt)
            af[mt] = *(const bf16x8*)(Ab + (wm + mt * 16 + l16) * 32 + quad * 8);
#pragma unroll
        for (int nt = 0; nt < 4; ++nt)
            bfr[nt] = *(const bf16x8*)(Bb + (wn + nt * 16 + l16) * 32 + quad * 8);
#pragma unroll
        for (int mt = 0; mt < 4; ++mt)
#pragma unroll
            for (int nt = 0; nt < 4; ++nt)
                acc[mt][nt] = MFMA16(af[mt], bfr[nt], acc[mt][nt]);
    }

#pragma unroll
    for (int mt = 0; mt < 4; ++mt)
#pragma unroll
        for (int nt = 0; nt < 4; ++nt) {
            const int row0 = bm + wm + mt * 16 + quad * 4;
            const int col = bn + wn + nt * 16 + l16;
            u16x4 pk;
#pragma unroll
            for (int r = 0; r < 4; ++r) {
                const float v0 = acc[mt][nt][r];
                if (OUT_MODE == 0) {
                    ((float*)Cv)[(size_t)(row0 + r) * N + col] = v0 * alpha;
                } else if (OUT_MODE == 3) {
                    if (col < 2048)
                        ((unsigned short*)Cv)[(size_t)(row0 + r) * 2048 + col] = f2bf(v0 * alpha);
                    else
                        Ct[(size_t)(row0 + r) * 512 + (col - 2048)] = f2bf(v0);
                } else {
                    const unsigned short b = f2bf(v0 * alpha);
                    ((unsigned short*)Cv)[(size_t)(row0 + r) * N + col] = b;
                    pk[r] = b;
                }
            }
            if (OUT_MODE == 2) {
                const size_t ti =
                    ((size_t)((row0 >> 11) * (N >> 7) + (col >> 7)) * 128 + (col & 127)) * 2048 +
                    (row0 & 2047);
                *(u16x4*)(Ct + ti) = pk;
            }
        }
}

// ---------------- flash attention, S^T formulation, no-max softmax ----------------
// R13: T15 att[2] cross-tile pipeline. KVBLK=32 (64 tiles), 4-deep 16KB K/V buffers
// (same 64KB LDS, 2 blk/CU). Per tile: QK^T(kt) -> PV(kt-1) -> SM(kt); PV(kt-1)'s
// 16 MFMA are independent of SM(kt)'s VALU chain -> scheduler hides softmax under
// MFMA (m214-v36 mechanism). pfr double-state statically unrolled (pfrA/pfrB).
// Per-tile ratios invariant vs R12 (16 b128 / 32 MFMA / 16 exp2 per wave): R10's
// LDS-traffic trap avoided. V tile now [128][32], chunk-XOR (d>>1)&3 (2-way, free).
// [R12 lesson: issue-slot trims don't pay -- kernel was dependency-structure-bound:
//  serial ds_read->QK^T->SM->PV chain in barrier lockstep at 2 waves/SIMD.]
// [R10/R7: occupancy is structurally 8 waves/CU at nt=2 -- grid has 2048 waves.]
// Grid (16 qt, 32 bh) XCD-chunked; 4 waves; wave owns 32 q-rows.
// gload_lds staging + pre-swizzled sources; in-register P; base-2 no-max softmax.
// Writes output IN-PLACE over Q.
__global__ __launch_bounds__(256, 2) void k_attn(const unsigned short* __restrict__ Q,
                                                 const unsigned short* __restrict__ KV,
                                                 const unsigned short* __restrict__ KVT,
                                                 unsigned short* __restrict__ O) {
    __shared__ alignas(16) unsigned short Ks[4 * 32 * 128];   // [buf][kr][d], swizzled
    __shared__ alignas(16) unsigned short Vt[4 * 128 * 32];   // [buf][d][kr], swizzled

    const int tid = threadIdx.x;
    const int wave = tid >> 6, lane = tid & 63;
    const int l16 = lane & 15, quad = lane >> 4;
    const int l8 = l16 & 7;
    // bijective XCD-chunk swizzle: XCD k owns bh in [4k, 4k+4) -> KV slice L2-resident.
    const int lid = blockIdx.x + (blockIdx.y << 4);
    const int wid = ((lid & 7) << 6) + (lid >> 3);
    const int qt = wid & 15;
    const int bh = wid >> 4;
    const size_t tokbase = (size_t)(bh >> 4) * 2048;
    const int hcol = (bh & 15) * 128;
    const unsigned short* kvt_head = KVT + (size_t)bh * (128 * 2048);

    bf16x8 qf[2][4];
    const int qrow0 = qt * 128 + wave * 32;
#pragma unroll
    for (int nt = 0; nt < 2; ++nt) {
        const unsigned short* qp =
            Q + (tokbase + qrow0 + nt * 16 + l16) * 2048 + hcol + quad * 8;
#pragma unroll
        for (int kd = 0; kd < 4; ++kd) qf[nt][kd] = *(const bf16x8*)(qp + kd * 32);
    }

    const f32x4 fzero = {0.f, 0.f, 0.f, 0.f};
    f32x4 o_acc[8][2];  // O^T[d=dt*16+quad*4+r][q=nt*16+l16]
#pragma unroll
    for (int dt = 0; dt < 8; ++dt)
#pragma unroll
        for (int nt = 0; nt < 2; ++nt) o_acc[dt][nt] = fzero;
    float l_i[2] = {0.f, 0.f};  // per-lane partial; quad-reduced once in epilogue

    auto KsL = (__attribute__((address_space(3))) unsigned short*)Ks;
    auto VtL = (__attribute__((address_space(3))) unsigned short*)Vt;

    // staging geometry (per 256-thread round, KVBLK=32):
    //  K: 32 rows x 16 chunks = 512 slots (2/thread); slot=p*256+tid, r=slot>>4,
    //     cd=slot&15; r&7 p-invariant -> csK = (cd&8)|((cd&7)^(r&7)).
    //  V: 128 d-rows x 4 chunks = 512 slots; d=slot>>2, cv=slot&3; (d>>1)&3
    //     p-invariant -> csV = cv ^ ((d>>1)&3).   (bank-checked: reads 2-way, free)
    const int r4 = tid >> 4, cdK = tid & 15;
    const int csK = (cdK & 8) | ((cdK & 7) ^ (r4 & 7));
    const int dv = tid >> 2, cvV = tid & 3;
    const int csV = cvV ^ ((tid >> 3) & 3);
    const unsigned short* kp0 = KV + (tokbase + r4) * 2048 + hcol + csK * 8;
    const unsigned short* vp0 = kvt_head + (size_t)dv * 2048 + csV * 8;

    auto stage = [&](int kt) {
        auto Kb = KsL + (kt & 3) * (32 * 128) + tid * 8;
        auto Vb = VtL + (kt & 3) * (128 * 32) + tid * 8;
        const unsigned short* kp = kp0 + (size_t)kt * (32 * 2048);
        const unsigned short* vp = vp0 + kt * 32;
#pragma unroll
        for (int p = 0; p < 2; ++p) {
            __builtin_amdgcn_global_load_lds(
                (const __attribute__((address_space(1))) void*)(kp + p * (16 * 2048)),
                (__attribute__((address_space(3))) void*)(Kb + p * 2048), 16, 0, 0);
            __builtin_amdgcn_global_load_lds(
                (const __attribute__((address_space(1))) void*)(vp + (size_t)p * (64 * 2048)),
                (__attribute__((address_space(3))) void*)(Vb + p * 2048), 16, 0, 0);
        }
    };

    const int vsw = (quad ^ ((l16 >> 1) & 3)) * 8;  // V read chunk-slot (swizzled)

    // ---- pipeline stages as lambdas (static indices everywhere) ----
    f32x4 st[2][2];
    auto qk = [&](int kt) {
        const unsigned short* Kb = Ks + (kt & 3) * (32 * 128);
#pragma unroll
        for (int mt = 0; mt < 2; ++mt)
#pragma unroll
            for (int nt = 0; nt < 2; ++nt) st[mt][nt] = fzero;
#pragma unroll
        for (int kd = 0; kd < 4; ++kd)
#pragma unroll
            for (int mt = 0; mt < 2; ++mt) {
                const int c = kd * 4 + quad;
                const int sw = (c & 8) | ((c & 7) ^ l8);
                const bf16x8 kf = *(const bf16x8*)(Kb + (mt * 16 + l16) * 128 + sw * 8);
                st[mt][0] = MFMA16(kf, qf[0][kd], st[mt][0]);
                st[mt][1] = MFMA16(kf, qf[1][kd], st[mt][1]);
            }
    };
    auto pv = [&](int kt, bf16x8 (&pfr)[2]) {
        const unsigned short* Vb = Vt + (kt & 3) * (128 * 32);
#pragma unroll
        for (int dt = 0; dt < 8; ++dt) {
            const bf16x8 vf = *(const bf16x8*)(Vb + (dt * 16 + l16) * 32 + vsw);
            o_acc[dt][0] = MFMA16(vf, pfr[0], o_acc[dt][0]);
            o_acc[dt][1] = MFMA16(vf, pfr[1], o_acc[dt][1]);
        }
    };
    auto sm = [&](bf16x8 (&pfr)[2]) {
#pragma unroll
        for (int nt = 0; nt < 2; ++nt) {
            float p[2][4];
            float rs = 0.f;
#pragma unroll
            for (int mt = 0; mt < 2; ++mt)
#pragma unroll
                for (int r = 0; r < 4; ++r) {
                    p[mt][r] = fexp2(st[mt][nt][r]);
                    rs += p[mt][r];
                }
            l_i[nt] += rs;
            unsigned int aw0, aw1, bw0, bw1;
            asm("v_cvt_pk_bf16_f32 %0, %1, %2" : "=v"(aw0) : "v"(p[0][0]), "v"(p[0][1]));
            asm("v_cvt_pk_bf16_f32 %0, %1, %2" : "=v"(aw1) : "v"(p[0][2]), "v"(p[0][3]));
            asm("v_cvt_pk_bf16_f32 %0, %1, %2" : "=v"(bw0) : "v"(p[1][0]), "v"(p[1][1]));
            asm("v_cvt_pk_bf16_f32 %0, %1, %2" : "=v"(bw1) : "v"(p[1][2]), "v"(p[1][3]));
            const u32x2 e0 = plswap32(aw0, bw0);
            const u32x2 e1 = plswap32(aw1, bw1);
            const u32x2 f0 = plswap16(e0.x, e0.y);
            const u32x2 f1 = plswap16(e1.x, e1.y);
            const u32x4 w = {f0.x, f1.x, f0.y, f1.y};
            pfr[nt] = __builtin_bit_cast(bf16x8, w);
        }
    };

    bf16x8 pfrA[2], pfrB[2];

    // ---- prologue: tiles 0,1 staged; peel kt=0 (no PV yet) ----
    stage(0);
    stage(1);
    __syncthreads();
    stage(2);
    __builtin_amdgcn_s_setprio(1);
    qk(0);
    __builtin_amdgcn_s_setprio(0);
    sm(pfrA);

    // ---- main loop: pairs (odd ko uses pfrB, even ke uses pfrA) ----
    for (int kt2 = 1; kt2 <= 31; ++kt2) {
        const int ko = 2 * kt2 - 1;  // 1,3,...,61
        __syncthreads();
        stage(ko + 2);               // 3..63
        __builtin_amdgcn_s_setprio(1);
        qk(ko);
        pv(ko - 1, pfrA);            // prev tile's PV overlaps this tile's SM
        __builtin_amdgcn_s_setprio(0);
        sm(pfrB);

        const int ke = 2 * kt2;      // 2,4,...,62
        __syncthreads();
        if (ke < 62) stage(ke + 2);  // 4..62 (64 doesn't exist)
        __builtin_amdgcn_s_setprio(1);
        qk(ke);
        pv(ke - 1, pfrB);
        __builtin_amdgcn_s_setprio(0);
        sm(pfrA);
    }

    // ---- tail: tile 63 ----
    __syncthreads();
    __builtin_amdgcn_s_setprio(1);
    qk(63);
    pv(62, pfrA);
    __builtin_amdgcn_s_setprio(0);
    sm(pfrB);
    pv(63, pfrB);

    // ---- epilogue: quad-reduce l, O^T[d][q] -> O[tok][d], packed b64 stores
#pragma unroll
    for (int nt = 0; nt < 2; ++nt) {
        const float inv = 1.0f / quad_reduce(l_i[nt]);
        unsigned short* dst = O + (tokbase + qrow0 + nt * 16 + l16) * 2048 + hcol;
#pragma unroll
        for (int dt = 0; dt < 8; ++dt) {
            u16x4 pk;
#pragma unroll
            for (int r = 0; r < 4; ++r) pk[r] = f2bf(o_acc[dt][nt][r] * inv);
            *(u16x4*)(dst + dt * 16 + quad * 4) = pk;
        }
    }
}

// ---------------- host launcher ----------------
extern "C" void kernel_launch(void* const* d_in, const int* in_sizes, int n_in,
                              void* d_out, int out_size, void* d_ws, size_t ws_size,
                              hipStream_t stream) {
    const float* x = (const float*)d_in[0];
    const float* W_q = (const float*)d_in[1];
    const float* W_kvd = (const float*)d_in[2];
    const float* W_kvu = (const float*)d_in[3];
    const float* W_o = (const float*)d_in[4];

    // 72 MB workspace (lifetime-packed):
    //   [0,16M)   xb (dead after fused GEMM) -> kvT
    //   [16,32M)  qb (q; attn writes output in-place here)
    //   [32,48M)  kvb
    //   [48,56M)  Wo_t
    //   [56,66M)  Wcat_t [2560][2048] (dead after fused GEMM)
    //   [66,68M)  Wkvu_t
    //   [68,72M)  lat
    char* w = (char*)d_ws;
    unsigned short* xb = (unsigned short*)(w);
    unsigned short* kvT = xb;
    unsigned short* qb = (unsigned short*)(w + (size_t)16 * 1024 * 1024);
    unsigned short* kvb = (unsigned short*)(w + (size_t)32 * 1024 * 1024);
    unsigned short* Wo_t = (unsigned short*)(w + (size_t)48 * 1024 * 1024);
    unsigned short* Wcat_t = (unsigned short*)(w + (size_t)56 * 1024 * 1024);
    unsigned short* Wkvu_t = (unsigned short*)(w + (size_t)66 * 1024 * 1024);
    unsigned short* lat = (unsigned short*)(w + (size_t)68 * 1024 * 1024);

    // fused prep: x->bf16 + all weight transposes (one dispatch)
    k_prep<<<18432, 256, 0, stream>>>(x, W_q, W_kvd, W_kvu, W_o, xb, Wcat_t, Wkvu_t, Wo_t);

    // fused: q = (x@W_q)*(scale*log2e) -> qb ; latent = x@W_kv_down -> lat
    // alpha = log2(e)/sqrt(128): attn uses exp2 directly (exp fold).
    k_gemm_bt<3><<<dim3(32, 20), 256, 0, stream>>>(xb, Wcat_t, qb, lat, 4096, 2560, 2048,
                                                   0.12751743f);
    // kv = latent @ W_kv_up  (+ per-head transposed copy kvT; xb is dead now)
    k_gemm_bt<2><<<dim3(32, 16), 256, 0, stream>>>(lat, Wkvu_t, kvb, kvT, 4096, 2048, 512,
                                                   1.0f);
    // flash attention (output in-place over qb); R13: att[2] pipeline, KVBLK=32
    k_attn<<<dim3(16, 32), 256, 0, stream>>>(qb, kvb, kvT, qb);
    // out = attn @ W_o  (fp32 output)
    k_gemm_bt<0><<<dim3(32, 16), 256, 0, stream>>>(qb, Wo_t, d_out, nullptr, 4096, 2048, 2048,
                                                   1.0f);
}